// Round 15
// baseline (118.080 us; speedup 1.0000x reference)
//
#include <hip/hip_runtime.h>
#include <cstdint>
#include <cstddef>

// Problem constants
#define B_  16
#define C_  384
#define H_  48
#define W_  48
#define HW_ 2304        // 48*48

typedef __bf16 bf16x8 __attribute__((ext_vector_type(8)));
typedef float  f32x4  __attribute__((ext_vector_type(4)));
typedef unsigned short u16x8 __attribute__((ext_vector_type(8)));

typedef __attribute__((address_space(3))) void       lds_void;
typedef const __attribute__((address_space(1))) void gbl_void;

__device__ __forceinline__ unsigned short f2bf(float f) {
    union { float f; unsigned int u; } v; v.f = f;
    unsigned int r = v.u + 0x7fffu + ((v.u >> 16) & 1u);   // RNE
    return (unsigned short)(r >> 16);
}
__device__ __forceinline__ float bf2f(unsigned short u) {
    union { unsigned int u; float f; } v; v.u = ((unsigned int)u) << 16;
    return v.f;
}

// ---------------------------------------------------------------------------
// L1: tcast + weight-cast + fp32 pool, ONE launch, partitioned by block.
//   blocks [0,3456)    : x[b][c][p] fp32 -> xT[b][p][c] bf16   (R10-exact)
//   blocks [3456,3744) : Wv,Wp fp32 -> bf16                    (R10-exact)
//   blocks [3744,9888) : R1/R8-proven fp32 pool -> px, emb     (bc per block)
// All branches read-only on inputs; outputs disjoint -> race-free.
// ---------------------------------------------------------------------------
__global__ __launch_bounds__(256) void tcastw_pool_kernel(const float* __restrict__ x,
                                                          const float* __restrict__ Wv,
                                                          const float* __restrict__ Wp,
                                                          unsigned short* __restrict__ Wvb,
                                                          unsigned short* __restrict__ Wpb,
                                                          unsigned short* __restrict__ xT,
                                                          float* __restrict__ px,
                                                          float* __restrict__ emb) {
    __shared__ unsigned short tile[64][68];
    __shared__ float red[4];
    const int blk = blockIdx.x;
    const int t   = threadIdx.x;

    if (blk < 3456) {
        // ---- tcast (R10-exact body) ----
        const int b    = blk / 216;
        const int r216 = blk % 216;
        const int c0   = (r216 / 36) * 64;
        const int p0   = (r216 % 36) * 64;
        const float* xb = x + ((size_t)b * C_ + c0) * HW_ + p0;

#pragma unroll
        for (int pass = 0; pass < 4; ++pass) {
            const int cr = pass * 16 + (t >> 4);
            const int pc = (t & 15) * 4;
            const float4 v = *(const float4*)&xb[(size_t)cr * HW_ + pc];
            tile[pc + 0][cr] = f2bf(v.x); tile[pc + 1][cr] = f2bf(v.y);
            tile[pc + 2][cr] = f2bf(v.z); tile[pc + 3][cr] = f2bf(v.w);
        }
        __syncthreads();
        unsigned short* xTb = xT + ((size_t)b * HW_ + p0) * C_ + c0;
#pragma unroll
        for (int pass = 0; pass < 4; ++pass) {
            const int pr = pass * 16 + (t >> 4);
            const int cc = (t & 15) * 4;
            *(ushort4*)&xTb[(size_t)pr * C_ + cc] = *(const ushort4*)&tile[pr][cc];
        }
    } else if (blk < 3744) {
        // ---- castw (R10-exact body) ----
        const int cblk = blk - 3456;
        const float* s = (cblk < 144) ? Wv : Wp;
        unsigned short* d = (cblk < 144) ? Wvb : Wpb;
        const int i = ((cblk < 144 ? cblk : cblk - 144) * 256 + t) * 4;
        const float4 v = *(const float4*)&s[i];
        ushort4 o; o.x = f2bf(v.x); o.y = f2bf(v.y); o.z = f2bf(v.z); o.w = f2bf(v.w);
        *(ushort4*)&d[i] = o;
    } else {
        // ---- pool (R1/R8-proven fp32 body) ----
        const int bc = blk - 3744;
        const float* xp = x + (size_t)bc * HW_;

        float v[9];
#pragma unroll
        for (int r = 0; r < 9; ++r) {
            const int ri = r / 3, rj = r % 3;
            v[r] = xp[(ri * 16 + (t >> 4)) * W_ + rj * 16 + (t & 15)];
        }
        float total = 0.f;
#pragma unroll
        for (int r = 0; r < 9; ++r) {
            float s = v[r];
#pragma unroll
            for (int o = 32; o > 0; o >>= 1) s += __shfl_down(s, o);
            if ((t & 63) == 0) red[t >> 6] = s;
            __syncthreads();
            if (t == 0) {
                const float bs = red[0] + red[1] + red[2] + red[3];
                px[bc * 9 + r] = bs * (1.f / 256.f);
                total += bs;
            }
            __syncthreads();
        }
        if (t == 0) emb[bc] = total * (1.f / 2304.f);
    }
}

// ---------------------------------------------------------------------------
// L2: GEMM1 + small, ONE launch.
//   blocks [0,864)   : GEMM1 (R11-exact body, XCD swizzle q8=108 over 864)
//   blocks [864,912) : small projections (R13-verified 256-thread body,
//                      emb derived from px; LDS overlaid on As/Bs)
// gemm1 reads xT/Wvb; small reads px/Wq/Wk/Wg.  Outputs valueT vs kernT
// disjoint -> race-free.
// ---------------------------------------------------------------------------
__global__ __launch_bounds__(256) void gemm1_small_kernel(
        const unsigned short* __restrict__ xT,
        const unsigned short* __restrict__ Wvb,
        const float* __restrict__ bv,
        const float* __restrict__ px,
        const float* __restrict__ Wq, const float* __restrict__ bq,
        const float* __restrict__ Wk, const float* __restrict__ bk,
        const float* __restrict__ Wg, const float* __restrict__ bg,
        unsigned short* __restrict__ valueT,
        unsigned short* __restrict__ kernT) {
    __shared__ __align__(16) unsigned short As[128 * 64];   // 16 KB
    __shared__ __align__(16) unsigned short Bs[128 * 64];   // 16 KB
    const int t = threadIdx.x;

    if (blockIdx.x < 864) {
        // ---------------- GEMM1 (R11-exact) ----------------
        const int swz = (blockIdx.x & 7) * 108 + (blockIdx.x >> 3);   // bijective
        const int mtile = swz / 3;
        const int ntile = swz % 3;
        const int m0 = mtile * 128, n0 = ntile * 128;

        const int l = t & 63, w = t >> 6;
        f32x4 acc[4][4] = {};
        const int wm = w >> 1, wn = w & 1;

        const int srow = t >> 3;
        const int skc  = t & 7;
        const int gkc  = skc ^ (srow & 7);

        const int lr = l & 15;
        const int kq = l >> 4;
        const int xorv = lr & 7;

        for (int k0 = 0; k0 < 384; k0 += 64) {
#pragma unroll
            for (int j = 0; j < 4; ++j)
                __builtin_amdgcn_global_load_lds(
                    (gbl_void*)(xT + (size_t)(m0 + 32 * j + srow) * 384 + k0 + gkc * 8),
                    (lds_void*)(As + (32 * j + srow) * 64 + skc * 8), 16, 0, 0);
#pragma unroll
            for (int j = 0; j < 4; ++j)
                __builtin_amdgcn_global_load_lds(
                    (gbl_void*)(Wvb + (size_t)(n0 + 32 * j + srow) * 384 + k0 + gkc * 8),
                    (lds_void*)(Bs + (32 * j + srow) * 64 + skc * 8), 16, 0, 0);
            __syncthreads();

#pragma unroll
            for (int sub = 0; sub < 2; ++sub) {
                const int kc = sub * 4 + kq;
                const int ko = (kc ^ xorv) * 8;
                bf16x8 af[4], bfr[4];
#pragma unroll
                for (int f = 0; f < 4; ++f)
                    af[f] = *reinterpret_cast<const bf16x8*>(&As[(wm * 64 + f * 16 + lr) * 64 + ko]);
#pragma unroll
                for (int f = 0; f < 4; ++f)
                    bfr[f] = *reinterpret_cast<const bf16x8*>(&Bs[(wn * 64 + f * 16 + lr) * 64 + ko]);
#pragma unroll
                for (int fm = 0; fm < 4; ++fm)
#pragma unroll
                    for (int fn = 0; fn < 4; ++fn)
                        acc[fm][fn] = __builtin_amdgcn_mfma_f32_16x16x32_bf16(af[fm], bfr[fn], acc[fm][fn], 0, 0, 0);
            }
            __syncthreads();
        }

        const int lg = (l >> 4) * 4;
#pragma unroll
        for (int fm = 0; fm < 4; ++fm) {
            const int row = m0 + wm * 64 + fm * 16 + lg;
#pragma unroll
            for (int fn = 0; fn < 4; ++fn) {
                const int col = n0 + wn * 64 + fn * 16 + lr;
                const float cb = bv[col];
#pragma unroll
                for (int rr = 0; rr < 4; ++rr)
                    valueT[(size_t)(row + rr) * C_ + col] = f2bf(acc[fm][fn][rr] + cb);
            }
        }
    } else {
        // ---------------- small (R13-verified 256-thread body) ----------------
        const int sb  = blockIdx.x - 864;       // 0..47
        const int b   = sb / 3;
        const int ox0 = (sb % 3) * 128;

        float* px_l  = (float*)As;              // 3456 floats = 13.5 KB
        float* emb_l = (float*)Bs;              // 384 floats
        float* wg_l  = (float*)Bs + 384;        // 81 floats
        float* bg_l  = (float*)Bs + 465;        // 9 floats

        for (int idx = t; idx < C_ * 9; idx += 256) px_l[idx] = px[(size_t)b * C_ * 9 + idx];
        if (t < 81) wg_l[t] = Wg[t];
        if (t < 9)  bg_l[t] = bg[t];
        __syncthreads();
        for (int idx = t; idx < C_; idx += 256) {
            float s0 = 0.f;
#pragma unroll
            for (int p = 0; p < 9; ++p) s0 += px_l[idx * 9 + p];
            emb_l[idx] = s0 * (1.f / 9.f);
        }
        __syncthreads();

        if (t < 128) {
            const int o = ox0 + t;
            float accq[9];
#pragma unroll
            for (int p = 0; p < 9; ++p) accq[p] = bq[o];
            float acck = bk[o];
            const float* wq_row = Wq + (size_t)o * C_;
            const float* wk_row = Wk + (size_t)o * C_;
            for (int i = 0; i < C_; ++i) {
                const float w = wq_row[i];
#pragma unroll
                for (int p = 0; p < 9; ++p) accq[p] = fmaf(w, px_l[i * 9 + p], accq[p]);
                acck = fmaf(wk_row[i], emb_l[i], acck);
            }

            float kf[9], mean = 0.f;
#pragma unroll
            for (int q = 0; q < 9; ++q) {
                float a = bg_l[q];
#pragma unroll
                for (int p = 0; p < 9; ++p) a = fmaf(accq[p], wg_l[q * 9 + p], a);
                kf[q] = a; mean += a;
            }
            mean *= (1.f / 9.f);
            const float sig = 1.f / (1.f + expf(-acck));
#pragma unroll
            for (int q = 0; q < 9; ++q)
                kernT[((size_t)b * 9 + q) * C_ + o] = f2bf(kf[q] - sig * mean);
        }
    }
}

// ---------------------------------------------------------------------------
// bf16 MFMA GEMM (R4-exact) — used for GEMM2.
// ---------------------------------------------------------------------------
template<int BIAS_COL, bool OUT_BF16, int BMAJOR>
__global__ __launch_bounds__(256) void gemm_bt(const unsigned short* __restrict__ A,
                                               const unsigned short* __restrict__ Bt,
                                               const float* __restrict__ bias,
                                               void* __restrict__ Yv,
                                               int N, int nMt, int nNt, int perB,
                                               long long sA, long long sB, long long sY) {
    const int q8  = gridDim.x >> 3;
    const int swz = (blockIdx.x & 7) * q8 + (blockIdx.x >> 3);
    const int b   = swz / perB;
    const int r   = swz % perB;
    const int mtile = BMAJOR ? (r % nMt) : (r / nNt);
    const int ntile = BMAJOR ? (r / nMt) : (r % nNt);
    const int m0 = mtile * 128, n0 = ntile * 128;

    const int t = threadIdx.x;
    const int l = t & 63, w = t >> 6;
    const unsigned short* Ab = A + (size_t)b * sA;
    const unsigned short* Bb = Bt + (size_t)b * sB;

    __shared__ __align__(16) unsigned short As[128 * 64];
    __shared__ __align__(16) unsigned short Bs[128 * 64];

    f32x4 acc[4][4] = {};
    const int wm = w >> 1, wn = w & 1;

    const int srow = t >> 3;
    const int skc  = t & 7;
    const int gkc  = skc ^ (srow & 7);

    const int lr = l & 15;
    const int kq = l >> 4;
    const int xorv = lr & 7;

    for (int k0 = 0; k0 < 384; k0 += 64) {
#pragma unroll
        for (int j = 0; j < 4; ++j)
            __builtin_amdgcn_global_load_lds(
                (gbl_void*)(Ab + (size_t)(m0 + 32 * j + srow) * 384 + k0 + gkc * 8),
                (lds_void*)(As + (32 * j + srow) * 64 + skc * 8), 16, 0, 0);
#pragma unroll
        for (int j = 0; j < 4; ++j)
            __builtin_amdgcn_global_load_lds(
                (gbl_void*)(Bb + (size_t)(n0 + 32 * j + srow) * 384 + k0 + gkc * 8),
                (lds_void*)(Bs + (32 * j + srow) * 64 + skc * 8), 16, 0, 0);
        __syncthreads();

#pragma unroll
        for (int sub = 0; sub < 2; ++sub) {
            const int kc = sub * 4 + kq;
            const int ko = (kc ^ xorv) * 8;
            bf16x8 af[4], bfr[4];
#pragma unroll
            for (int f = 0; f < 4; ++f)
                af[f] = *reinterpret_cast<const bf16x8*>(&As[(wm * 64 + f * 16 + lr) * 64 + ko]);
#pragma unroll
            for (int f = 0; f < 4; ++f)
                bfr[f] = *reinterpret_cast<const bf16x8*>(&Bs[(wn * 64 + f * 16 + lr) * 64 + ko]);
#pragma unroll
            for (int fm = 0; fm < 4; ++fm)
#pragma unroll
                for (int fn = 0; fn < 4; ++fn)
                    acc[fm][fn] = __builtin_amdgcn_mfma_f32_16x16x32_bf16(af[fm], bfr[fn], acc[fm][fn], 0, 0, 0);
        }
        __syncthreads();
    }

    const int lg = (l >> 4) * 4;
#pragma unroll
    for (int fm = 0; fm < 4; ++fm) {
        const int row = m0 + wm * 64 + fm * 16 + lg;
#pragma unroll
        for (int fn = 0; fn < 4; ++fn) {
            const int col = n0 + wn * 64 + fn * 16 + lr;
            const float cb = BIAS_COL ? bias[col] : 0.f;
#pragma unroll
            for (int rr = 0; rr < 4; ++rr) {
                const float v = acc[fm][fn][rr] + (BIAS_COL ? cb : bias[row + rr]);
                if (OUT_BF16)
                    ((unsigned short*)Yv)[(size_t)b * sY + (size_t)(row + rr) * N + col] = f2bf(v);
                else
                    ((float*)Yv)[(size_t)b * sY + (size_t)(row + rr) * N + col] = v;
            }
        }
    }
}

// ---------------------------------------------------------------------------
// dwT v2 (R10/R14-exact): 4 consecutive same-row pixels x 8 channels/thread.
// ---------------------------------------------------------------------------
__global__ __launch_bounds__(256) void dwT_kernel(const unsigned short* __restrict__ vT,
                                                  const unsigned short* __restrict__ kT,
                                                  unsigned short* __restrict__ oT) {
    const int b = blockIdx.y;
    const int u = blockIdx.x * 256 + threadIdx.x;
    const int cg = u % 48;
    const int pg = u / 48;
    const int p0 = pg * 4;
    const int h  = p0 / W_;
    const int w0 = p0 % W_;
    const int c0 = cg * 8;
    const size_t base = (size_t)b * HW_ * C_;

    u16x8 kv[9];
#pragma unroll
    for (int q = 0; q < 9; ++q)
        kv[q] = *(const u16x8*)&kT[((size_t)b * 9 + q) * C_ + c0];

    const u16x8 zero = {};
    u16x8 v[3][6];
#pragma unroll
    for (int di = 0; di < 3; ++di) {
        const int hh = h + di - 1;
        const bool hok = (hh >= 0) && (hh < H_);
#pragma unroll
        for (int c = 0; c < 6; ++c) {
            const int wn = w0 + c - 1;
            const bool ok = hok && (wn >= 0) && (wn < W_);
            v[di][c] = ok ? *(const u16x8*)&vT[base + (size_t)(hh * W_ + wn) * C_ + c0]
                          : zero;
        }
    }

#pragma unroll
    for (int j = 0; j < 4; ++j) {
        float acc[8] = {};
#pragma unroll
        for (int di = 0; di < 3; ++di)
#pragma unroll
            for (int dj = 0; dj < 3; ++dj) {
                const int q = di * 3 + dj;
                const u16x8 vv = v[di][j + dj];
#pragma unroll
                for (int e = 0; e < 8; ++e)
                    acc[e] = fmaf(bf2f(vv[e]), bf2f(kv[q][e]), acc[e]);
            }
        u16x8 o;
#pragma unroll
        for (int e = 0; e < 8; ++e) o[e] = f2bf(acc[e]);
        *(u16x8*)&oT[base + (size_t)(p0 + j) * C_ + c0] = o;
    }
}

// ---------------------------------------------------------------------------
extern "C" void kernel_launch(void* const* d_in, const int* in_sizes, int n_in,
                              void* d_out, int out_size, void* d_ws, size_t ws_size,
                              hipStream_t stream) {
    const float* x  = (const float*)d_in[0];
    const float* Wq = (const float*)d_in[1];
    const float* bq = (const float*)d_in[2];
    const float* Wk = (const float*)d_in[3];
    const float* bk = (const float*)d_in[4];
    const float* Wv = (const float*)d_in[5];
    const float* bv = (const float*)d_in[6];
    const float* Wg = (const float*)d_in[7];
    const float* bg = (const float*)d_in[8];
    const float* Wp = (const float*)d_in[9];
    const float* bp = (const float*)d_in[10];
    float* out = (float*)d_out;

    char* ws = (char*)d_ws;
    const size_t bhwc2 = (size_t)B_ * HW_ * C_ * 2;          // 28,311,552 B
    unsigned short* xT     = (unsigned short*)ws;             // reused as out2T
    unsigned short* valueT = (unsigned short*)(ws + bhwc2);
    unsigned short* Wvb    = (unsigned short*)(ws + 2 * bhwc2);
    unsigned short* Wpb    = (unsigned short*)(ws + 2 * bhwc2 + 294912);
    float*          px     = (float*)(ws + 2 * bhwc2 + 2 * 294912);
    unsigned short* kernT  = (unsigned short*)(ws + 2 * bhwc2 + 2 * 294912 + 221184);
    float*          emb    = (float*)(ws + 2 * bhwc2 + 2 * 294912 + 221184 + 110592);
    unsigned short* out2T  = xT;   // xT dead after GEMM1

    // L1: tcast + weight-cast + fp32 pool (independent prep, one launch)
    tcastw_pool_kernel<<<9888, 256, 0, stream>>>(x, Wv, Wp, Wvb, Wpb, xT, px, emb);
    // L2: GEMM1 (blocks 0-863) + small projections (blocks 864-911)
    gemm1_small_kernel<<<912, 256, 0, stream>>>(
        xT, Wvb, bv, px, Wq, bq, Wk, bk, Wg, bg, valueT, kernT);
    // L3: depthwise dynamic 3x3
    dwT_kernel<<<dim3(108, B_), 256, 0, stream>>>(valueT, kernT, out2T);
    // L4: GEMM2: out[b][c][p] = Wp[c][:] . out2T[b][p][:] + bp[c]
    gemm_bt<0, false, 1><<<864, 256, 0, stream>>>(
        Wpb, out2T, bp, (void*)out, HW_, 3, 18, 54,
        0LL, (long long)HW_ * C_, (long long)C_ * HW_);
}

// Round 16
// 104.567 us; speedup vs baseline: 1.1292x; 1.1292x over previous
//
#include <hip/hip_runtime.h>
#include <cstdint>
#include <cstddef>

// Problem constants
#define B_  16
#define C_  384
#define H_  48
#define W_  48
#define HW_ 2304        // 48*48

typedef __bf16 bf16x8 __attribute__((ext_vector_type(8)));
typedef float  f32x4  __attribute__((ext_vector_type(4)));
typedef unsigned short u16x8 __attribute__((ext_vector_type(8)));

typedef __attribute__((address_space(3))) void       lds_void;
typedef const __attribute__((address_space(1))) void gbl_void;

__device__ __forceinline__ unsigned short f2bf(float f) {
    union { float f; unsigned int u; } v; v.f = f;
    unsigned int r = v.u + 0x7fffu + ((v.u >> 16) & 1u);   // RNE
    return (unsigned short)(r >> 16);
}
__device__ __forceinline__ float bf2f(unsigned short u) {
    union { unsigned int u; float f; } v; v.u = ((unsigned int)u) << 16;
    return v.f;
}

// ---------------------------------------------------------------------------
// tcastw (R10/R14-exact): tcast + weight-cast in ONE launch.
// ---------------------------------------------------------------------------
__global__ __launch_bounds__(256) void tcastw_kernel(const float* __restrict__ x,
                                                     const float* __restrict__ Wv,
                                                     const float* __restrict__ Wp,
                                                     unsigned short* __restrict__ Wvb,
                                                     unsigned short* __restrict__ Wpb,
                                                     unsigned short* __restrict__ xT) {
    __shared__ unsigned short tile[64][68];
    const int blk = blockIdx.x;
    const int t   = threadIdx.x;

    if (blk < 3456) {
        const int b    = blk / 216;
        const int r216 = blk % 216;
        const int c0   = (r216 / 36) * 64;
        const int p0   = (r216 % 36) * 64;
        const float* xb = x + ((size_t)b * C_ + c0) * HW_ + p0;

#pragma unroll
        for (int pass = 0; pass < 4; ++pass) {
            const int cr = pass * 16 + (t >> 4);
            const int pc = (t & 15) * 4;
            const float4 v = *(const float4*)&xb[(size_t)cr * HW_ + pc];
            tile[pc + 0][cr] = f2bf(v.x); tile[pc + 1][cr] = f2bf(v.y);
            tile[pc + 2][cr] = f2bf(v.z); tile[pc + 3][cr] = f2bf(v.w);
        }
        __syncthreads();
        unsigned short* xTb = xT + ((size_t)b * HW_ + p0) * C_ + c0;
#pragma unroll
        for (int pass = 0; pass < 4; ++pass) {
            const int pr = pass * 16 + (t >> 4);
            const int cc = (t & 15) * 4;
            *(ushort4*)&xTb[(size_t)pr * C_ + cc] = *(const ushort4*)&tile[pr][cc];
        }
    } else {
        const int cblk = blk - 3456;
        const float* s = (cblk < 144) ? Wv : Wp;
        unsigned short* d = (cblk < 144) ? Wvb : Wpb;
        const int i = ((cblk < 144 ? cblk : cblk - 144) * 256 + t) * 4;
        const float4 v = *(const float4*)&s[i];
        ushort4 o; o.x = f2bf(v.x); o.y = f2bf(v.y); o.z = f2bf(v.z); o.w = f2bf(v.w);
        *(ushort4*)&d[i] = o;
    }
}

// ---------------------------------------------------------------------------
// FUSED launch (R11/R14-exact): blocks [0,864) = GEMM1; [864,1728) = poolT.
// ---------------------------------------------------------------------------
__global__ __launch_bounds__(256) void gemm1_pool_kernel(const unsigned short* __restrict__ xT,
                                                         const unsigned short* __restrict__ Wvb,
                                                         const float* __restrict__ bv,
                                                         unsigned short* __restrict__ valueT,
                                                         float* __restrict__ px) {
    __shared__ __align__(16) unsigned short As[128 * 64];   // 16 KB
    __shared__ __align__(16) unsigned short Bs[128 * 64];   // 16 KB
    const int t = threadIdx.x;

    if (blockIdx.x < 864) {
        // ---------------- GEMM1 ----------------
        const int swz = (blockIdx.x & 7) * 108 + (blockIdx.x >> 3);   // bijective
        const int mtile = swz / 3;
        const int ntile = swz % 3;
        const int m0 = mtile * 128, n0 = ntile * 128;

        const int l = t & 63, w = t >> 6;
        f32x4 acc[4][4] = {};
        const int wm = w >> 1, wn = w & 1;

        const int srow = t >> 3;
        const int skc  = t & 7;
        const int gkc  = skc ^ (srow & 7);

        const int lr = l & 15;
        const int kq = l >> 4;
        const int xorv = lr & 7;

        for (int k0 = 0; k0 < 384; k0 += 64) {
#pragma unroll
            for (int j = 0; j < 4; ++j)
                __builtin_amdgcn_global_load_lds(
                    (gbl_void*)(xT + (size_t)(m0 + 32 * j + srow) * 384 + k0 + gkc * 8),
                    (lds_void*)(As + (32 * j + srow) * 64 + skc * 8), 16, 0, 0);
#pragma unroll
            for (int j = 0; j < 4; ++j)
                __builtin_amdgcn_global_load_lds(
                    (gbl_void*)(Wvb + (size_t)(n0 + 32 * j + srow) * 384 + k0 + gkc * 8),
                    (lds_void*)(Bs + (32 * j + srow) * 64 + skc * 8), 16, 0, 0);
            __syncthreads();

#pragma unroll
            for (int sub = 0; sub < 2; ++sub) {
                const int kc = sub * 4 + kq;
                const int ko = (kc ^ xorv) * 8;
                bf16x8 af[4], bfr[4];
#pragma unroll
                for (int f = 0; f < 4; ++f)
                    af[f] = *reinterpret_cast<const bf16x8*>(&As[(wm * 64 + f * 16 + lr) * 64 + ko]);
#pragma unroll
                for (int f = 0; f < 4; ++f)
                    bfr[f] = *reinterpret_cast<const bf16x8*>(&Bs[(wn * 64 + f * 16 + lr) * 64 + ko]);
#pragma unroll
                for (int fm = 0; fm < 4; ++fm)
#pragma unroll
                    for (int fn = 0; fn < 4; ++fn)
                        acc[fm][fn] = __builtin_amdgcn_mfma_f32_16x16x32_bf16(af[fm], bfr[fn], acc[fm][fn], 0, 0, 0);
            }
            __syncthreads();
        }

        const int lg = (l >> 4) * 4;
#pragma unroll
        for (int fm = 0; fm < 4; ++fm) {
            const int row = m0 + wm * 64 + fm * 16 + lg;
#pragma unroll
            for (int fn = 0; fn < 4; ++fn) {
                const int col = n0 + wn * 64 + fn * 16 + lr;
                const float cb = bv[col];
#pragma unroll
                for (int rr = 0; rr < 4; ++rr)
                    valueT[(size_t)(row + rr) * C_ + col] = f2bf(acc[fm][fn][rr] + cb);
            }
        }
    } else {
        // ---------------- poolT (R10-exact body) ----------------
        const int pb = blockIdx.x - 864;
        const int r  = pb % 9;
        const int c0 = ((pb / 9) % 6) * 64;
        const int b  = pb / 54;
        const int wv = t >> 6;
        const int l  = t & 63;
        const int i  = l >> 3;
        const int cg = l & 7;
        const int ri = r / 3, rj = r % 3;
        const int cbase = c0 + cg * 8;

        float* s = (float*)As;

        float acc[8] = {};
#pragma unroll
        for (int k = 0; k < 8; ++k) {
            const int pix = wv * 64 + i + k * 8;
            const int h = ri * 16 + (pix >> 4), w2 = rj * 16 + (pix & 15);
            const u16x8 v = *(const u16x8*)&xT[((size_t)b * HW_ + h * W_ + w2) * C_ + cbase];
#pragma unroll
            for (int e = 0; e < 8; ++e) acc[e] += bf2f(v[e]);
        }
#pragma unroll
        for (int m = 8; m <= 32; m <<= 1)
#pragma unroll
            for (int e = 0; e < 8; ++e) acc[e] += __shfl_xor(acc[e], m, 64);
        if (i == 0)
#pragma unroll
            for (int e = 0; e < 8; ++e) s[wv * 64 + cg * 8 + e] = acc[e];
        __syncthreads();
        if (t < 64) {
            const float tot = s[0 * 64 + t] + s[1 * 64 + t] + s[2 * 64 + t] + s[3 * 64 + t];
            px[((size_t)b * C_ + c0 + t) * 9 + r] = tot * (1.f / 256.f);
        }
    }
}

// ---------------------------------------------------------------------------
// small v2: 8-way i-split.  block (128 o-lanes, 8 i-slices) = 1024 threads,
// grid (3, 16).  Each thread accumulates a 48-iteration partial (serial
// chain 8x shorter than v1's 384); LDS reduction combines; ys=0 finishes.
// ---------------------------------------------------------------------------
__global__ __launch_bounds__(1024) void small_kernel(const float* __restrict__ px,
                                                     const float* __restrict__ Wq, const float* __restrict__ bq,
                                                     const float* __restrict__ Wk, const float* __restrict__ bk,
                                                     const float* __restrict__ Wg, const float* __restrict__ bg,
                                                     unsigned short* __restrict__ kernT) {
    const int b   = blockIdx.y;
    const int tx  = threadIdx.x;        // 0..127  (o-lane)
    const int ys  = threadIdx.y;        // 0..7    (i-slice)
    const int tid = ys * 128 + tx;
    const int o   = blockIdx.x * 128 + tx;

    __shared__ float px_l[C_ * 9];      // 13824 B
    __shared__ float emb_l[C_];
    __shared__ float wg_l[81];
    __shared__ float bg_l[9];
    __shared__ float part_q[7][128][9]; // 32256 B (slices 1..7)
    __shared__ float part_k[7][128];

    for (int idx = tid; idx < C_ * 9; idx += 1024) px_l[idx] = px[(size_t)b * C_ * 9 + idx];
    if (tid < 81) wg_l[tid] = Wg[tid];
    if (tid < 9)  bg_l[tid] = bg[tid];
    __syncthreads();
    if (tid < C_) {
        float s0 = 0.f;
#pragma unroll
        for (int p = 0; p < 9; ++p) s0 += px_l[tid * 9 + p];
        emb_l[tid] = s0 * (1.f / 9.f);
    }
    __syncthreads();

    float accq[9] = {};
    float acck = 0.f;
    const float* wq_row = Wq + (size_t)o * C_;
    const float* wk_row = Wk + (size_t)o * C_;
    const int i0 = ys * 48;
#pragma unroll 4
    for (int i = i0; i < i0 + 48; ++i) {
        const float w = wq_row[i];
#pragma unroll
        for (int p = 0; p < 9; ++p) accq[p] = fmaf(w, px_l[i * 9 + p], accq[p]);
        acck = fmaf(wk_row[i], emb_l[i], acck);
    }

    if (ys > 0) {
#pragma unroll
        for (int p = 0; p < 9; ++p) part_q[ys - 1][tx][p] = accq[p];
        part_k[ys - 1][tx] = acck;
    }
    __syncthreads();

    if (ys == 0) {
#pragma unroll
        for (int s = 0; s < 7; ++s) {
#pragma unroll
            for (int p = 0; p < 9; ++p) accq[p] += part_q[s][tx][p];
            acck += part_k[s][tx];
        }
        const float bqo = bq[o];
#pragma unroll
        for (int p = 0; p < 9; ++p) accq[p] += bqo;
        acck += bk[o];

        float kf[9], mean = 0.f;
#pragma unroll
        for (int q = 0; q < 9; ++q) {
            float a = bg_l[q];
#pragma unroll
            for (int p = 0; p < 9; ++p) a = fmaf(accq[p], wg_l[q * 9 + p], a);
            kf[q] = a; mean += a;
        }
        mean *= (1.f / 9.f);
        const float sig = 1.f / (1.f + expf(-acck));
#pragma unroll
        for (int q = 0; q < 9; ++q)
            kernT[((size_t)b * 9 + q) * C_ + o] = f2bf(kf[q] - sig * mean);
    }
}

// ---------------------------------------------------------------------------
// bf16 MFMA GEMM (R4-exact) — used for GEMM2.
// ---------------------------------------------------------------------------
template<int BIAS_COL, bool OUT_BF16, int BMAJOR>
__global__ __launch_bounds__(256) void gemm_bt(const unsigned short* __restrict__ A,
                                               const unsigned short* __restrict__ Bt,
                                               const float* __restrict__ bias,
                                               void* __restrict__ Yv,
                                               int N, int nMt, int nNt, int perB,
                                               long long sA, long long sB, long long sY) {
    const int q8  = gridDim.x >> 3;
    const int swz = (blockIdx.x & 7) * q8 + (blockIdx.x >> 3);
    const int b   = swz / perB;
    const int r   = swz % perB;
    const int mtile = BMAJOR ? (r % nMt) : (r / nNt);
    const int ntile = BMAJOR ? (r / nMt) : (r % nNt);
    const int m0 = mtile * 128, n0 = ntile * 128;

    const int t = threadIdx.x;
    const int l = t & 63, w = t >> 6;
    const unsigned short* Ab = A + (size_t)b * sA;
    const unsigned short* Bb = Bt + (size_t)b * sB;

    __shared__ __align__(16) unsigned short As[128 * 64];
    __shared__ __align__(16) unsigned short Bs[128 * 64];

    f32x4 acc[4][4] = {};
    const int wm = w >> 1, wn = w & 1;

    const int srow = t >> 3;
    const int skc  = t & 7;
    const int gkc  = skc ^ (srow & 7);

    const int lr = l & 15;
    const int kq = l >> 4;
    const int xorv = lr & 7;

    for (int k0 = 0; k0 < 384; k0 += 64) {
#pragma unroll
        for (int j = 0; j < 4; ++j)
            __builtin_amdgcn_global_load_lds(
                (gbl_void*)(Ab + (size_t)(m0 + 32 * j + srow) * 384 + k0 + gkc * 8),
                (lds_void*)(As + (32 * j + srow) * 64 + skc * 8), 16, 0, 0);
#pragma unroll
        for (int j = 0; j < 4; ++j)
            __builtin_amdgcn_global_load_lds(
                (gbl_void*)(Bb + (size_t)(n0 + 32 * j + srow) * 384 + k0 + gkc * 8),
                (lds_void*)(Bs + (32 * j + srow) * 64 + skc * 8), 16, 0, 0);
        __syncthreads();

#pragma unroll
        for (int sub = 0; sub < 2; ++sub) {
            const int kc = sub * 4 + kq;
            const int ko = (kc ^ xorv) * 8;
            bf16x8 af[4], bfr[4];
#pragma unroll
            for (int f = 0; f < 4; ++f)
                af[f] = *reinterpret_cast<const bf16x8*>(&As[(wm * 64 + f * 16 + lr) * 64 + ko]);
#pragma unroll
            for (int f = 0; f < 4; ++f)
                bfr[f] = *reinterpret_cast<const bf16x8*>(&Bs[(wn * 64 + f * 16 + lr) * 64 + ko]);
#pragma unroll
            for (int fm = 0; fm < 4; ++fm)
#pragma unroll
                for (int fn = 0; fn < 4; ++fn)
                    acc[fm][fn] = __builtin_amdgcn_mfma_f32_16x16x32_bf16(af[fm], bfr[fn], acc[fm][fn], 0, 0, 0);
        }
        __syncthreads();
    }

    const int lg = (l >> 4) * 4;
#pragma unroll
    for (int fm = 0; fm < 4; ++fm) {
        const int row = m0 + wm * 64 + fm * 16 + lg;
#pragma unroll
        for (int fn = 0; fn < 4; ++fn) {
            const int col = n0 + wn * 64 + fn * 16 + lr;
            const float cb = BIAS_COL ? bias[col] : 0.f;
#pragma unroll
            for (int rr = 0; rr < 4; ++rr) {
                const float v = acc[fm][fn][rr] + (BIAS_COL ? cb : bias[row + rr]);
                if (OUT_BF16)
                    ((unsigned short*)Yv)[(size_t)b * sY + (size_t)(row + rr) * N + col] = f2bf(v);
                else
                    ((float*)Yv)[(size_t)b * sY + (size_t)(row + rr) * N + col] = v;
            }
        }
    }
}

// ---------------------------------------------------------------------------
// dwT v2 (R10/R14-exact): 4 consecutive same-row pixels x 8 channels/thread.
// ---------------------------------------------------------------------------
__global__ __launch_bounds__(256) void dwT_kernel(const unsigned short* __restrict__ vT,
                                                  const unsigned short* __restrict__ kT,
                                                  unsigned short* __restrict__ oT) {
    const int b = blockIdx.y;
    const int u = blockIdx.x * 256 + threadIdx.x;
    const int cg = u % 48;
    const int pg = u / 48;
    const int p0 = pg * 4;
    const int h  = p0 / W_;
    const int w0 = p0 % W_;
    const int c0 = cg * 8;
    const size_t base = (size_t)b * HW_ * C_;

    u16x8 kv[9];
#pragma unroll
    for (int q = 0; q < 9; ++q)
        kv[q] = *(const u16x8*)&kT[((size_t)b * 9 + q) * C_ + c0];

    const u16x8 zero = {};
    u16x8 v[3][6];
#pragma unroll
    for (int di = 0; di < 3; ++di) {
        const int hh = h + di - 1;
        const bool hok = (hh >= 0) && (hh < H_);
#pragma unroll
        for (int c = 0; c < 6; ++c) {
            const int wn = w0 + c - 1;
            const bool ok = hok && (wn >= 0) && (wn < W_);
            v[di][c] = ok ? *(const u16x8*)&vT[base + (size_t)(hh * W_ + wn) * C_ + c0]
                          : zero;
        }
    }

#pragma unroll
    for (int j = 0; j < 4; ++j) {
        float acc[8] = {};
#pragma unroll
        for (int di = 0; di < 3; ++di)
#pragma unroll
            for (int dj = 0; dj < 3; ++dj) {
                const int q = di * 3 + dj;
                const u16x8 vv = v[di][j + dj];
#pragma unroll
                for (int e = 0; e < 8; ++e)
                    acc[e] = fmaf(bf2f(vv[e]), bf2f(kv[q][e]), acc[e]);
            }
        u16x8 o;
#pragma unroll
        for (int e = 0; e < 8; ++e) o[e] = f2bf(acc[e]);
        *(u16x8*)&oT[base + (size_t)(p0 + j) * C_ + c0] = o;
    }
}

// ---------------------------------------------------------------------------
extern "C" void kernel_launch(void* const* d_in, const int* in_sizes, int n_in,
                              void* d_out, int out_size, void* d_ws, size_t ws_size,
                              hipStream_t stream) {
    const float* x  = (const float*)d_in[0];
    const float* Wq = (const float*)d_in[1];
    const float* bq = (const float*)d_in[2];
    const float* Wk = (const float*)d_in[3];
    const float* bk = (const float*)d_in[4];
    const float* Wv = (const float*)d_in[5];
    const float* bv = (const float*)d_in[6];
    const float* Wg = (const float*)d_in[7];
    const float* bg = (const float*)d_in[8];
    const float* Wp = (const float*)d_in[9];
    const float* bp = (const float*)d_in[10];
    float* out = (float*)d_out;

    char* ws = (char*)d_ws;
    const size_t bhwc2 = (size_t)B_ * HW_ * C_ * 2;          // 28,311,552 B
    unsigned short* xT     = (unsigned short*)ws;             // reused as out2T
    unsigned short* valueT = (unsigned short*)(ws + bhwc2);
    unsigned short* Wvb    = (unsigned short*)(ws + 2 * bhwc2);
    unsigned short* Wpb    = (unsigned short*)(ws + 2 * bhwc2 + 294912);
    float*          px     = (float*)(ws + 2 * bhwc2 + 2 * 294912);
    unsigned short* kernT  = (unsigned short*)(ws + 2 * bhwc2 + 2 * 294912 + 221184);
    unsigned short* out2T  = xT;   // xT dead after GEMM1

    // 1. tcast + weight-cast
    tcastw_kernel<<<3744, 256, 0, stream>>>(x, Wv, Wp, Wvb, Wpb, xT);
    // 2. GEMM1 (blocks 0-863) + poolT (blocks 864-1727) in one launch
    gemm1_pool_kernel<<<1728, 256, 0, stream>>>(xT, Wvb, bv, valueT, px);
    // 3. dynamic kernels — 8-way i-split, 1024 threads
    small_kernel<<<dim3(3, B_), dim3(128, 8), 0, stream>>>(px, Wq, bq, Wk, bk, Wg, bg, kernT);
    // 4. depthwise dynamic 3x3
    dwT_kernel<<<dim3(108, B_), 256, 0, stream>>>(valueT, kernT, out2T);
    // 5. GEMM2: out[b][c][p] = Wp[c][:] . out2T[b][p][:] + bp[c]
    gemm_bt<0, false, 1><<<864, 256, 0, stream>>>(
        Wpb, out2T, bp, (void*)out, HW_, 3, 18, 54,
        0LL, (long long)HW_ * C_, (long long)C_ * HW_);
}